// Round 12
// baseline (1016.621 us; speedup 1.0000x reference)
//
#include <hip/hip_runtime.h>
#include <math.h>

// Problem constants (x: (5,1,256,64,64) f32)
constexpr int NIMG = 5;
constexpr int CCH  = 256;   // channels (both c and d)
constexpr int HWP  = 4096;  // H*W
constexpr int PT   = CCH * HWP;  // elems per image = 1048576

// R5-proven skeleton: 32 d x 64 p per block, BK=16, 2-phase double buffer,
// micro-tile 2d x 4p x 5 images dual-acc = 80 acc regs, launch_bounds(256,2).
// R12 delta ONLY: w staged as packed pre-summed b128 {ws0,ws1,w20,w21} via
// registers+ds_write -> compute reads 1xb128 (was 2xb64) and skips the
// per-cc w1+w2 adds. Same fp32 values/chain -> bit-identical output.
constexpr int BD = 32;
constexpr int BP = 64;
constexpr int BK = 16;
constexpr int NSTEP = CCH / BK;   // 16

// Async global->LDS, 16B/lane. LDS dest is wave-uniform base; HW adds lane*16.
__device__ __forceinline__ void gload16(const float* g, float* l) {
    __builtin_amdgcn_global_load_lds(
        (const __attribute__((address_space(1))) unsigned int*)g,
        (__attribute__((address_space(3))) unsigned int*)l, 16, 0, 0);
}

__global__ __launch_bounds__(256, 2) void fused_all(
    const float* __restrict__ x, const float* __restrict__ w,
    const float* __restrict__ bias, float* __restrict__ out)
{
    const int t  = threadIdx.x;
    const int tp = t & 15;   // p-frag: cols p0 + tp*4 .. +3
    const int td = t >> 4;   // d-frag: rows d0 + td*2, td*2+1
    const int p0 = blockIdx.x * BP;
    const int d0 = blockIdx.y * BD;

    __shared__ float xs [2][NIMG][BK][BP];  // 2 x 20 KB
    __shared__ float wpk[2][BK][16][4];     // 2 x 4 KB: {ws0,ws1,w20,w21}

    float acc_s[NIMG][2][4] = {};  // sum_c x*(W1+W2)
    float acc_2[NIMG][2][4] = {};  // sum_c x*W2

    const int wv = t >> 6, l = t & 63;
    const int xr = l >> 4, xc = (l & 15) * 4;  // x chunk: 4 rows x 64 floats
    const int cc_w = t >> 4, sl_w = t & 15;    // w slot: (cc, d-pair)

    float2 w1r, w2r;  // in-flight w regs for the next step

    // x staging: 20 chunks of 1 KB (n, k); wave wv stages chunks wv+4s.
    auto stage_x = [&](int b, int c0) {
        #pragma unroll
        for (int s = 0; s < NIMG; ++s) {
            const int g = wv + 4 * s;
            const int n = g >> 2, k = g & 3;
            gload16(&x[(size_t)n * PT + (size_t)(c0 + k * 4 + xr) * HWP + p0 + xc],
                    &xs[b][n][k * 4][0]);
        }
    };
    // w: each thread owns one (cc, d-pair) slot; 2 coalesced float2 loads.
    auto wload = [&](int c0) {
        w1r = *reinterpret_cast<const float2*>(
            &w[(size_t)(c0 + cc_w) * CCH + d0 + sl_w * 2]);
        w2r = *reinterpret_cast<const float2*>(
            &w[(size_t)(CCH + c0 + cc_w) * CCH + d0 + sl_w * 2]);
    };
    auto wwrite = [&](int b) {
        const float4 pk = {w1r.x + w2r.x, w1r.y + w2r.y, w2r.x, w2r.y};
        *reinterpret_cast<float4*>(&wpk[b][cc_w][sl_w][0]) = pk;
    };

    // prologue: fill buffer 0
    wload(0);            // 2 vm
    stage_x(0, 0);       // 5 vm
    wwrite(0);           // auto-waits its regs (vmcnt(5)); ds_write
    asm volatile("s_waitcnt lgkmcnt(0)" ::: "memory");

    for (int st = 0; st < NSTEP; ++st) {
        const int cur = st & 1;
        if (st + 1 < NSTEP) {
            wload((st + 1) * BK);            // 2 vm (deepest latency first)
            stage_x(cur ^ 1, (st + 1) * BK); // 5 vm
            // outstanding = old x(5) + new w(2) + new x(5); drain old x:
            asm volatile("s_waitcnt vmcnt(7)" ::: "memory");
        } else {
            asm volatile("s_waitcnt vmcnt(0)" ::: "memory");
        }
        __builtin_amdgcn_s_barrier();   // xs[cur] + wpk[cur] ready (all waves)

        #pragma unroll
        for (int cc = 0; cc < BK; ++cc) {
            const float4 pk = *reinterpret_cast<const float4*>(&wpk[cur][cc][td][0]);
            const float wsa[2] = {pk.x, pk.y};
            const float w2a[2] = {pk.z, pk.w};
            #pragma unroll
            for (int n = 0; n < NIMG; ++n) {
                const float4 xv = *reinterpret_cast<const float4*>(&xs[cur][n][cc][tp * 4]);
                const float xa[4] = {xv.x, xv.y, xv.z, xv.w};
                #pragma unroll
                for (int i = 0; i < 2; ++i) {
                    #pragma unroll
                    for (int j = 0; j < 4; ++j) {
                        acc_s[n][i][j] = fmaf(wsa[i], xa[j], acc_s[n][i][j]);
                        acc_2[n][i][j] = fmaf(w2a[i], xa[j], acc_2[n][i][j]);
                    }
                }
            }
        }

        if (st + 1 < NSTEP) {
            wwrite(cur ^ 1);   // regs arrived (auto vmcnt(5); x prefetch stays)
            asm volatile("s_waitcnt lgkmcnt(0)" ::: "memory");
        }
        __builtin_amdgcn_s_barrier();   // all waves done reading cur
    }

    // ---------------- fused epilogue: edges + threshold + reduce ----------------
    #pragma unroll
    for (int r = 0; r < 2; ++r) {
        const int d = d0 + td * 2 + r;
        const float bd = bias[d];
        const size_t base = (size_t)d * HWP + p0 + tp * 4;

        float xa[NIMG][4], ua[NIMG][4], va[NIMG][4];
        #pragma unroll
        for (int n = 0; n < NIMG; ++n) {
            const float4 xv = *reinterpret_cast<const float4*>(&x[(size_t)n * PT + base]);
            const float xt[4] = {xv.x, xv.y, xv.z, xv.w};
            #pragma unroll
            for (int q = 0; q < 4; ++q) {
                xa[n][q] = xt[q];
                ua[n][q] = xt[q] - acc_s[n][r][q] - bd;
                va[n][q] = acc_2[n][r][q];
            }
        }

        #pragma unroll
        for (int i = 0; i < NIMG; ++i) {
            float ho[4];
            #pragma unroll
            for (int q = 0; q < 4; ++q) {
                float e[NIMG];
                float sumsq = 0.0f;
                #pragma unroll
                for (int j = 0; j < NIMG; ++j) {
                    e[j] = fabsf(ua[j][q] - va[i][q]);
                    sumsq = fmaf(e[j], e[j], sumsq);
                }
                const float m = fmaxf(sqrtf(sumsq), 1e-12f);
                float h = 0.0f;
                #pragma unroll
                for (int j = 0; j < NIMG; ++j) {
                    const float en = e[j] / m;
                    if (en > 0.35f) h = fmaf(e[j], xa[j][q], h);
                }
                ho[q] = h;
            }
            const float4 ov = {ho[0], ho[1], ho[2], ho[3]};
            *reinterpret_cast<float4*>(&out[(size_t)i * PT + base]) = ov;
        }
    }
}

extern "C" void kernel_launch(void* const* d_in, const int* in_sizes, int n_in,
                              void* d_out, int out_size, void* d_ws, size_t ws_size,
                              hipStream_t stream) {
    const float* x    = (const float*)d_in[0];
    const float* w    = (const float*)d_in[1];
    const float* bias = (const float*)d_in[2];
    float* out = (float*)d_out;

    // grid.x = 64 p-slices, grid.y = 8 d-tiles; linear wgid%8 == x%8 pins all
    // 8 d-tiles sharing a p-slice of x to one XCD (L2 reuse of x reads).
    dim3 g(HWP / BP, CCH / BD);   // 64 x 8 = 512 blocks, 2 per CU
    fused_all<<<g, 256, 0, stream>>>(x, w, bias, out);
}

// Round 13
// 82.248 us; speedup vs baseline: 12.3604x; 12.3604x over previous
//
#include <hip/hip_runtime.h>
#include <math.h>

// Problem constants (x: (5,1,256,64,64) f32)
constexpr int NIMG = 5;
constexpr int CCH  = 256;   // channels (both c and d)
constexpr int HWP  = 4096;  // H*W
constexpr int PT   = CCH * HWP;  // elems per image = 1048576

// Tiling: 32 d x 64 p per block, K-step 16, double-buffered, n-loop in block.
constexpr int BD = 32;
constexpr int BP = 64;
constexpr int BK = 16;
constexpr int NSTEP = CCH / BK;   // 16

// Async global->LDS, 16B/lane. LDS dest is wave-uniform base; HW adds lane*16.
__device__ __forceinline__ void gload16(const float* g, float* l) {
    __builtin_amdgcn_global_load_lds(
        (const __attribute__((address_space(1))) unsigned int*)g,
        (__attribute__((address_space(3))) unsigned int*)l, 16, 0, 0);
}

// -----------------------------------------------------------------------------
// Fully fused: per block (d0,p0), all 5 images; 2-phase double-buffered K-loop
// with counted vmcnt (loads in flight across barriers — no vmcnt(0) drain
// mid-loop). Math chain identical to passing R4 version -> bit-identical out.
//   acc_s[n] = sum_c x[n,c,p]*(W1+W2)[c,d],  acc_2[n] = sum_c x[n,c,p]*W2[c,d]
//   u = x - acc_s - b ; v = acc_2 ; e=|u[j]-v[i]| ; thresholded weighted sum.
// -----------------------------------------------------------------------------
__global__ __launch_bounds__(256, 2) void fused_all(
    const float* __restrict__ x, const float* __restrict__ w,
    const float* __restrict__ bias, float* __restrict__ out)
{
    const int t  = threadIdx.x;
    const int tp = t & 15;   // p-frag: cols p0 + tp*4 .. +3
    const int td = t >> 4;   // d-frag: rows d0 + td*2, td*2+1
    const int p0 = blockIdx.x * BP;
    const int d0 = blockIdx.y * BD;

    __shared__ float xs [2][NIMG][BK][BP];  // 2 x 20 KB
    __shared__ float w1s[2][BK][BD];        // 2 x 2 KB
    __shared__ float w2s[2][BK][BD];        // 2 x 2 KB

    float acc_s[NIMG][2][4] = {};
    float acc_2[NIMG][2][4] = {};

    const int wv = t >> 6, l = t & 63;
    const int xr = l >> 4, xc = (l & 15) * 4;  // x chunk: 4 rows x 64 floats
    const int wr = l >> 3, wc = (l & 7) * 4;   // w chunk: 8 rows x 32 floats

    // Stage one K-step (c0) into buffer b. 6 gload16 per wave, uniform:
    //  - 5 x-chunks: global chunk id g = wv + 4s, s=0..4 -> n=g>>2, k=g&3
    //  - 1 w-chunk : wv<2 -> w1 chunk wv ; else w2 chunk wv-2
    auto stage = [&](int b, int c0) {
        #pragma unroll
        for (int s = 0; s < NIMG; ++s) {
            const int g = wv + 4 * s;
            const int n = g >> 2, k = g & 3;
            gload16(&x[(size_t)n * PT + (size_t)(c0 + k * 4 + xr) * HWP + p0 + xc],
                    &xs[b][n][k * 4][0]);
        }
        if (wv < 2) {
            gload16(&w[(size_t)(c0 + wv * 8 + wr) * CCH + d0 + wc],
                    &w1s[b][wv * 8][0]);
        } else {
            gload16(&w[(size_t)(256 + c0 + (wv - 2) * 8 + wr) * CCH + d0 + wc],
                    &w2s[b][(wv - 2) * 8][0]);
        }
    };

    stage(0, 0);

    for (int st = 0; st < NSTEP; ++st) {
        const int cur = st & 1;
        if (st + 1 < NSTEP) {
            stage(cur ^ 1, (st + 1) * BK);
            asm volatile("s_waitcnt vmcnt(6)" ::: "memory");  // step st's loads done
        } else {
            asm volatile("s_waitcnt vmcnt(0)" ::: "memory");
        }
        __builtin_amdgcn_s_barrier();   // buffer cur fully staged (all waves)

        #pragma unroll
        for (int cc = 0; cc < BK; ++cc) {
            const float2 w1v = *reinterpret_cast<const float2*>(&w1s[cur][cc][td * 2]);
            const float2 w2v = *reinterpret_cast<const float2*>(&w2s[cur][cc][td * 2]);
            const float w2a[2] = {w2v.x, w2v.y};
            const float wsa[2] = {w1v.x + w2v.x, w1v.y + w2v.y};
            #pragma unroll
            for (int n = 0; n < NIMG; ++n) {
                const float4 xv = *reinterpret_cast<const float4*>(&xs[cur][n][cc][tp * 4]);
                const float xa[4] = {xv.x, xv.y};
                const float xb[4] = {xv.x, xv.y, xv.z, xv.w};
                #pragma unroll
                for (int i = 0; i < 2; ++i) {
                    #pragma unroll
                    for (int j = 0; j < 4; ++j) {
                        acc_s[n][i][j] = fmaf(wsa[i], xb[j], acc_s[n][i][j]);
                        acc_2[n][i][j] = fmaf(w2a[i], xb[j], acc_2[n][i][j]);
                    }
                }
            }
        }
        __builtin_amdgcn_s_barrier();   // compute done before re-staging cur^1
    }

    // ---------------- fused epilogue: edges + threshold + reduce ----------------
    #pragma unroll
    for (int r = 0; r < 2; ++r) {
        const int d = d0 + td * 2 + r;
        const float bd = bias[d];
        const size_t base = (size_t)d * HWP + p0 + tp * 4;

        float xa[NIMG][4], ua[NIMG][4], va[NIMG][4];
        #pragma unroll
        for (int n = 0; n < NIMG; ++n) {
            const float4 xv = *reinterpret_cast<const float4*>(&x[(size_t)n * PT + base]);
            const float xt[4] = {xv.x, xv.y, xv.z, xv.w};
            #pragma unroll
            for (int q = 0; q < 4; ++q) {
                xa[n][q] = xt[q];
                ua[n][q] = xt[q] - acc_s[n][r][q] - bd;
                va[n][q] = acc_2[n][r][q];
            }
        }

        #pragma unroll
        for (int i = 0; i < NIMG; ++i) {
            float ho[4];
            #pragma unroll
            for (int q = 0; q < 4; ++q) {
                float e[NIMG];
                float sumsq = 0.0f;
                #pragma unroll
                for (int j = 0; j < NIMG; ++j) {
                    e[j] = fabsf(ua[j][q] - va[i][q]);
                    sumsq = fmaf(e[j], e[j], sumsq);
                }
                const float m = fmaxf(sqrtf(sumsq), 1e-12f);
                float h = 0.0f;
                #pragma unroll
                for (int j = 0; j < NIMG; ++j) {
                    const float en = e[j] / m;
                    if (en > 0.35f) h = fmaf(e[j], xa[j][q], h);
                }
                ho[q] = h;
            }
            const float2 ov0 = {ho[0], ho[1]};
            const float2 ov1 = {ho[2], ho[3]};
            *reinterpret_cast<float2*>(&out[(size_t)i * PT + base])     = ov0;
            *reinterpret_cast<float2*>(&out[(size_t)i * PT + base + 2]) = ov1;
        }
    }
}

extern "C" void kernel_launch(void* const* d_in, const int* in_sizes, int n_in,
                              void* d_out, int out_size, void* d_ws, size_t ws_size,
                              hipStream_t stream) {
    const float* x    = (const float*)d_in[0];
    const float* w    = (const float*)d_in[1];
    const float* bias = (const float*)d_in[2];
    float* out = (float*)d_out;

    dim3 g(HWP / BP, CCH / BD);   // 64 x 8 = 512 blocks
    fused_all<<<g, 256, 0, stream>>>(x, w, bias, out);
}